// Round 2
// baseline (365.957 us; speedup 1.0000x reference)
//
#include <hip/hip_runtime.h>
#include <math.h>

#define T 32
#define NEGS 0.1f
#define EPS 1e-5f
#define NREG 33

// ws layout:
//   doubles at byte 0: [0]=sum_y [1]=sum_y2 [2..34]=hist S0 [35..67]=hist S1 [68..100]=hist S2
//   float y[k]            at byte 1024
//   float gP[33*32],gQ[33*32] at byte 1024+4k

__device__ __forceinline__ float rcp_fast(float x) { return __builtin_amdgcn_rcpf(x); }
__device__ __forceinline__ float sigm(float x) { return rcp_fast(1.0f + __expf(-x)); }
__device__ __forceinline__ float tanh_fast(float x) {
    float t = __expf(2.0f * fabsf(x));
    float r = 1.0f - 2.0f * rcp_fast(t + 1.0f);   // t=inf -> 1, no NaN
    return copysignf(r, x);
}
__device__ __forceinline__ float lrelu(float x) { return x > 0.0f ? x : NEGS * x; }
__device__ __forceinline__ float f4c(const float4 f, int c) {
    switch (c & 3) { case 0: return f.x; case 1: return f.y; case 2: return f.z; default: return f.w; }
}

// BN1 fold: y1_j = lrelu(a_j*(y-my) + b_j); indicator y>tau_j (flip for a<0)
__device__ __forceinline__ void bn1_params(const float* __restrict__ W1,
                                           const float* __restrict__ g1,
                                           const float* __restrict__ b1,
                                           const double* __restrict__ wsd, int k, int j,
                                           float& my, float& vy, float& a, float& b,
                                           float& tau, int& flip)
{
    my = (float)(wsd[0] / k);
    vy = (float)(wsd[1] / k) - my * my;
    float wj = W1[j];
    a = g1[j] * wj * rsqrtf(fmaf(wj * wj, vy, EPS));
    b = b1[j];
    if (a > 0.0f)      { tau = my - b / a; flip = 0; }
    else if (a < 0.0f) { tau = my - b / a; flip = 1; }
    else               { tau = (b > 0.0f ? -__builtin_inff() : __builtin_inff()); flip = 0; }
}

__global__ __launch_bounds__(256, 1)
void lstm_kernel(const float* __restrict__ r, const float* __restrict__ v,
                 const float* __restrict__ u,
                 const float* __restrict__ wih0, const float* __restrict__ wihr,
                 const float* __restrict__ whhp,
                 float* __restrict__ out, double* __restrict__ wsd,
                 float* __restrict__ wsy, int k)
{
    const int s = blockIdx.x * 256 + threadIdx.x;

    float wi0[4][21];
#pragma unroll
    for (int g = 0; g < 4; ++g)
#pragma unroll
        for (int j = 0; j < 21; ++j) wi0[g][j] = wih0[g * 21 + j];
    float wir[4][4];
#pragma unroll
    for (int l = 0; l < 4; ++l)
#pragma unroll
        for (int g = 0; g < 4; ++g) wir[l][g] = wihr[l * 4 + g];
    float whh[5][4];
#pragma unroll
    for (int l = 0; l < 5; ++l)
#pragma unroll
        for (int g = 0; g < 4; ++g) whh[l][g] = whhp[l * 4 + g];

    const float4* r4 = reinterpret_cast<const float4*>(r + (size_t)s * (T * 9));
    const float4* v4 = reinterpret_cast<const float4*>(v + (size_t)s * (T * 6));
    const float4* u4 = reinterpret_cast<const float4*>(u + (size_t)s * (T * 6));

    float4 rb[9], vb[6], ub[6];
#pragma unroll
    for (int q = 0; q < 9; ++q) rb[q] = r4[q];
#pragma unroll
    for (int q = 0; q < 6; ++q) vb[q] = v4[q];
#pragma unroll
    for (int q = 0; q < 6; ++q) ub[q] = u4[q];

    float h[5] = {0.f, 0.f, 0.f, 0.f, 0.f};
    float c[5] = {0.f, 0.f, 0.f, 0.f, 0.f};
    float y0 = 0.f;

#pragma unroll
    for (int cb = 0; cb < 8; ++cb) {
        // input-dot contributions for this chunk (independent FMA work)
        float xg[4][4];
#pragma unroll
        for (int dt = 0; dt < 4; ++dt) {
#pragma unroll
            for (int g = 0; g < 4; ++g) {
                float acc = 0.f;
#pragma unroll
                for (int j = 0; j < 9; ++j) acc = fmaf(wi0[g][j], f4c(rb[(dt * 9 + j) >> 2], dt * 9 + j), acc);
#pragma unroll
                for (int j = 0; j < 6; ++j) acc = fmaf(wi0[g][9 + j], f4c(vb[(dt * 6 + j) >> 2], dt * 6 + j), acc);
#pragma unroll
                for (int j = 0; j < 6; ++j) acc = fmaf(wi0[g][15 + j], f4c(ub[(dt * 6 + j) >> 2], dt * 6 + j), acc);
                xg[dt][g] = acc;
            }
        }
        // prefetch next chunk while recurrence runs
        if (cb < 7) {
#pragma unroll
            for (int q = 0; q < 9; ++q) rb[q] = r4[(cb + 1) * 9 + q];
#pragma unroll
            for (int q = 0; q < 6; ++q) vb[q] = v4[(cb + 1) * 6 + q];
#pragma unroll
            for (int q = 0; q < 6; ++q) ub[q] = u4[(cb + 1) * 6 + q];
        }
        // serial recurrence (4 timesteps)
#pragma unroll
        for (int dt = 0; dt < 4; ++dt) {
            float g0 = fmaf(whh[0][0], h[0], xg[dt][0]);
            float g1 = fmaf(whh[0][1], h[0], xg[dt][1]);
            float g2 = fmaf(whh[0][2], h[0], xg[dt][2]);
            float g3 = fmaf(whh[0][3], h[0], xg[dt][3]);
            {
                float ii = sigm(g0), ff = sigm(g1);
                float gg = tanh_fast(g2), oo = sigm(g3);
                c[0] = ff * c[0] + ii * gg;
                h[0] = oo * tanh_fast(c[0]);
            }
            float xin = h[0];
#pragma unroll
            for (int l = 1; l < 5; ++l) {
                float a0 = fmaf(wir[l - 1][0], xin, whh[l][0] * h[l]);
                float a1 = fmaf(wir[l - 1][1], xin, whh[l][1] * h[l]);
                float a2 = fmaf(wir[l - 1][2], xin, whh[l][2] * h[l]);
                float a3 = fmaf(wir[l - 1][3], xin, whh[l][3] * h[l]);
                float ii = sigm(a0), ff = sigm(a1);
                float gg = tanh_fast(a2), oo = sigm(a3);
                c[l] = ff * c[l] + ii * gg;
                h[l] = oo * tanh_fast(c[l]);
                xin = h[l];
            }
            if (cb == 0 && dt == 0) y0 = h[4];
        }
    }

    // outputs: dv at [0,6k); hT at [6k,11k); cT at [11k,16k)
#pragma unroll
    for (int l = 0; l < 5; ++l) {
        out[(size_t)6 * k + (size_t)l * k + s] = h[l];
        out[(size_t)11 * k + (size_t)l * k + s] = c[l];
    }
    wsy[s] = y0;

    float ys = y0, yq = y0 * y0;
#pragma unroll
    for (int off = 32; off; off >>= 1) {
        ys += __shfl_down(ys, off);
        yq += __shfl_down(yq, off);
    }
    __shared__ float pS[4], pQ[4];
    const int wid = threadIdx.x >> 6, lane = threadIdx.x & 63;
    if (lane == 0) { pS[wid] = ys; pQ[wid] = yq; }
    __syncthreads();
    if (threadIdx.x == 0) {
        atomicAdd(&wsd[0], (double)(pS[0] + pS[1] + pS[2] + pS[3]));
        atomicAdd(&wsd[1], (double)(pQ[0] + pQ[1] + pQ[2] + pQ[3]));
    }
}

// 33-region histogram of (count, sum(yc), sum(yc^2))
__global__ __launch_bounds__(256)
void hist_kernel(const float* __restrict__ W1, const float* __restrict__ g1,
                 const float* __restrict__ b1, double* __restrict__ wsd,
                 const float* __restrict__ wsy, int k)
{
    __shared__ float sTau[32];
    __shared__ float sH[3 * NREG];
    __shared__ float sMy;
    const int tid = threadIdx.x;
    if (tid < 3 * NREG) sH[tid] = 0.f;
    if (tid < 32) {
        float my, vy, a, b, tau; int flip;
        bn1_params(W1, g1, b1, wsd, k, tid, my, vy, a, b, tau, flip);
        sTau[tid] = tau;
        if (tid == 0) sMy = my;
    }
    __syncthreads();
    const int s = blockIdx.x * 256 + tid;
    const float y = wsy[s];
    const float yc = y - sMy;
    int rgn = 0;
#pragma unroll
    for (int j = 0; j < 32; ++j) rgn += (y > sTau[j]) ? 1 : 0;
    atomicAdd(&sH[rgn], 1.0f);
    atomicAdd(&sH[NREG + rgn], yc);
    atomicAdd(&sH[2 * NREG + rgn], yc * yc);
    __syncthreads();
    if (tid < 3 * NREG) atomicAdd(&wsd[2 + tid], (double)sH[tid]);
}

// single block: BN2 stats from region moments + per-region P/Q tables
__global__ __launch_bounds__(256)
void tables_kernel(const float* __restrict__ W1, const float* __restrict__ g1,
                   const float* __restrict__ b1, const float* __restrict__ W2,
                   const float* __restrict__ g2, const float* __restrict__ b2,
                   const double* __restrict__ wsd, float* __restrict__ gPQ, int k)
{
    __shared__ float sA[32], sB[32], sTau[32];
    __shared__ int sRank[32], sFlip[32];
    __shared__ float sS0[NREG], sS1[NREG], sS2[NREG];
    __shared__ float sW2[1024];
    __shared__ float sSumY1[32];
    __shared__ float sM[1024];          // M[j][l] = sum_s y1_j y1_l
    __shared__ float sI2[32], sM2v[32], sB2[32];
    const int tid = threadIdx.x;

    for (int i = tid; i < 1024; i += 256) sW2[i] = W2[i];
    if (tid < NREG) {
        sS0[tid] = (float)wsd[2 + tid];
        sS1[tid] = (float)wsd[2 + NREG + tid];
        sS2[tid] = (float)wsd[2 + 2 * NREG + tid];
    }
    if (tid < 32) {
        float my, vy, a, b, tau; int flip;
        bn1_params(W1, g1, b1, wsd, k, tid, my, vy, a, b, tau, flip);
        sA[tid] = a; sB[tid] = b; sTau[tid] = tau; sFlip[tid] = flip;
        sB2[tid] = b2[tid];
    }
    __syncthreads();
    if (tid < 32) {
        int rk = 0;
        float tj = sTau[tid];
#pragma unroll
        for (int l = 0; l < 32; ++l)
            rk += (sTau[l] < tj || (sTau[l] == tj && l < tid)) ? 1 : 0;
        sRank[tid] = rk;
    }
    __syncthreads();
    if (tid < 32) {
        // sum over samples of y1_j via region moments
        const int rk = sRank[tid], fl = sFlip[tid];
        const float a = sA[tid], b = sB[tid];
        float acc = 0.f;
        for (int rg = 0; rg < NREG; ++rg) {
            float m = (((rk < rg) ? 1 : 0) != fl) ? 1.0f : NEGS;
            acc += m * (a * sS1[rg] + b * sS0[rg]);
        }
        sSumY1[tid] = acc;
    }
    // M matrix: 1024 pairs over 256 threads
    for (int p = tid; p < 1024; p += 256) {
        const int j = p >> 5, l = p & 31;
        const int rj = sRank[j], fj = sFlip[j];
        const int rl = sRank[l], flp = sFlip[l];
        const float aj = sA[j], bj = sB[j], al = sA[l], bl = sB[l];
        const float caa = aj * al, cab = aj * bl + al * bj, cbb = bj * bl;
        float acc = 0.f;
        for (int rg = 0; rg < NREG; ++rg) {
            float mj = (((rj < rg) ? 1 : 0) != fj) ? 1.0f : NEGS;
            float ml = (((rl < rg) ? 1 : 0) != flp) ? 1.0f : NEGS;
            acc += mj * ml * (caa * sS2[rg] + cab * sS1[rg] + cbb * sS0[rg]);
        }
        sM[p] = acc;
    }
    __syncthreads();
    if (tid < 32) {
        const int i = tid;
        float s2 = 0.f, ss2 = 0.f;
#pragma unroll
        for (int j = 0; j < 32; ++j) {
            float wij = sW2[i * 32 + j];
            s2 = fmaf(wij, sSumY1[j], s2);
            float tj = 0.f;
#pragma unroll
            for (int l = 0; l < 32; ++l) tj = fmaf(sW2[i * 32 + l], sM[j * 32 + l], tj);
            ss2 = fmaf(wij, tj, ss2);
        }
        float m2 = s2 / k;
        float v2 = ss2 / k - m2 * m2;
        sM2v[i] = m2;
        sI2[i] = g2[i] * rsqrtf(v2 + EPS);
    }
    __syncthreads();
    // tables: P[r][i] = I2_i * sum_j W2_ij m_j(r) a_j ; Q folds the rest
    for (int idx = tid; idx < NREG * 32; idx += 256) {
        const int rg = idx >> 5, i = idx & 31;
        float Ai = 0.f, Bi = 0.f;
#pragma unroll
        for (int j = 0; j < 32; ++j) {
            float m = (((sRank[j] < rg) ? 1 : 0) != sFlip[j]) ? 1.0f : NEGS;
            float w = sW2[i * 32 + j] * m;
            Ai = fmaf(w, sA[j], Ai);
            Bi = fmaf(w, sB[j], Bi);
        }
        gPQ[idx] = sI2[i] * Ai;
        gPQ[NREG * 32 + idx] = sI2[i] * (Bi - sM2v[i]) + sB2[i];
    }
}

__global__ __launch_bounds__(256)
void final_kernel(const float* __restrict__ W1, const float* __restrict__ g1,
                  const float* __restrict__ b1, const float* __restrict__ W3,
                  const double* __restrict__ wsd, const float* __restrict__ wsy,
                  const float* __restrict__ gPQ, float* __restrict__ out, int k)
{
    __shared__ float sTau[32], sW3[192], sMy;
    __shared__ float sP[NREG][33], sQ[NREG][33];   // pad to 33 to break bank conflicts
    const int tid = threadIdx.x;
    for (int idx = tid; idx < NREG * 32; idx += 256) {
        const int rg = idx >> 5, i = idx & 31;
        sP[rg][i] = gPQ[idx];
        sQ[rg][i] = gPQ[NREG * 32 + idx];
    }
    if (tid < 192) sW3[tid] = W3[tid];
    if (tid < 32) {
        float my, vy, a, b, tau; int flip;
        bn1_params(W1, g1, b1, wsd, k, tid, my, vy, a, b, tau, flip);
        sTau[tid] = tau;
        if (tid == 0) sMy = my;
    }
    __syncthreads();
    const int s = blockIdx.x * 256 + tid;
    const float y = wsy[s];
    const float yc = y - sMy;
    int rgn = 0;
#pragma unroll
    for (int j = 0; j < 32; ++j) rgn += (y > sTau[j]) ? 1 : 0;
    float dv[6] = {0.f, 0.f, 0.f, 0.f, 0.f, 0.f};
#pragma unroll
    for (int i = 0; i < 32; ++i) {
        float y2 = lrelu(fmaf(sP[rgn][i], yc, sQ[rgn][i]));
#pragma unroll
        for (int m = 0; m < 6; ++m) dv[m] = fmaf(sW3[m * 32 + i], y2, dv[m]);
    }
#pragma unroll
    for (int m = 0; m < 6; ++m) out[(size_t)s * 6 + m] = dv[m];
}

extern "C" void kernel_launch(void* const* d_in, const int* in_sizes, int n_in,
                              void* d_out, int out_size, void* d_ws, size_t ws_size,
                              hipStream_t stream)
{
    const float* r    = (const float*)d_in[0];
    const float* v    = (const float*)d_in[1];
    const float* u    = (const float*)d_in[2];
    const float* wih0 = (const float*)d_in[3];
    const float* wihr = (const float*)d_in[4];
    const float* whhp = (const float*)d_in[5];
    const float* W1   = (const float*)d_in[6];
    const float* g1v  = (const float*)d_in[7];
    const float* b1v  = (const float*)d_in[8];
    const float* W2   = (const float*)d_in[9];
    const float* g2v  = (const float*)d_in[10];
    const float* b2v  = (const float*)d_in[11];
    const float* W3   = (const float*)d_in[12];

    const int k = in_sizes[0] / (T * 9);   // 65536
    float* out = (float*)d_out;
    double* wsd = (double*)d_ws;
    float* wsy = (float*)((char*)d_ws + 1024);
    float* gPQ = (float*)((char*)d_ws + 1024 + (size_t)k * 4);

    hipMemsetAsync(d_ws, 0, 1024, stream);

    const int blocks = k / 256;
    lstm_kernel<<<blocks, 256, 0, stream>>>(r, v, u, wih0, wihr, whhp, out, wsd, wsy, k);
    hist_kernel<<<blocks, 256, 0, stream>>>(W1, g1v, b1v, wsd, wsy, k);
    tables_kernel<<<1, 256, 0, stream>>>(W1, g1v, b1v, W2, g2v, b2v, wsd, gPQ, k);
    final_kernel<<<blocks, 256, 0, stream>>>(W1, g1v, b1v, W3, wsd, wsy, gPQ, out, k);
}

// Round 3
// 262.029 us; speedup vs baseline: 1.3966x; 1.3966x over previous
//
#include <hip/hip_runtime.h>
#include <math.h>

#define T 32
#define NEGS 0.1f
#define EPS 1e-5f
#define NREG 33

// ws layout (big path):
//   [0,1024): double accum[101]: [0]=sum_y [1]=sum_y2 [2..100]=hist S0/S1/S2
//   [1024, 1024+4k): float y[k]
//   [1024+4k, +16kT): float4 xg[T][k]
//   then float gPQ[2*NREG*32]
// fallback path: gPQ right after wsy.

__device__ __forceinline__ float rcp_fast(float x) { return __builtin_amdgcn_rcpf(x); }
__device__ __forceinline__ float sigm(float x) { return rcp_fast(1.0f + __expf(-x)); }
__device__ __forceinline__ float tanh_fast(float x) {
    float t = __expf(2.0f * fabsf(x));
    float r = 1.0f - 2.0f * rcp_fast(t + 1.0f);
    return copysignf(r, x);
}
__device__ __forceinline__ float lrelu(float x) { return x > 0.0f ? x : NEGS * x; }

__device__ __forceinline__ void bn1_params(const float* __restrict__ W1,
                                           const float* __restrict__ g1,
                                           const float* __restrict__ b1,
                                           const double* __restrict__ wsd, int k, int j,
                                           float& my, float& vy, float& a, float& b,
                                           float& tau, int& flip)
{
    my = (float)(wsd[0] / k);
    vy = (float)(wsd[1] / k) - my * my;
    float wj = W1[j];
    a = g1[j] * wj * rsqrtf(fmaf(wj * wj, vy, EPS));
    b = b1[j];
    if (a > 0.0f)      { tau = my - b / a; flip = 0; }
    else if (a < 0.0f) { tau = my - b / a; flip = 1; }
    else               { tau = (b > 0.0f ? -__builtin_inff() : __builtin_inff()); flip = 0; }
}

// ---------------- Kernel A: gate precompute (coalesced, massively parallel) ----
// thread <-> (sample, t); block = 8 samples x 32 timesteps
__global__ __launch_bounds__(256)
void gates_kernel(const float* __restrict__ r, const float* __restrict__ v,
                  const float* __restrict__ u, const float* __restrict__ wih0,
                  float4* __restrict__ xg, int k)
{
    __shared__ float lds[32 * 36];
    const int tid = threadIdx.x;
    const int s0 = blockIdx.x * 8;
    const int sl = tid >> 5, t = tid & 31;
    const size_t st = (size_t)(s0 + sl) * T + t;

    float wi0[4][21];
#pragma unroll
    for (int g = 0; g < 4; ++g)
#pragma unroll
        for (int j = 0; j < 21; ++j) wi0[g][j] = wih0[g * 21 + j];

    const float* rp = r + st * 9;
    const float* vp = v + st * 6;
    const float* up = u + st * 6;
    float x[21];
#pragma unroll
    for (int j = 0; j < 9; ++j) x[j] = rp[j];
#pragma unroll
    for (int j = 0; j < 6; ++j) x[9 + j] = vp[j];
#pragma unroll
    for (int j = 0; j < 6; ++j) x[15 + j] = up[j];

    float4 g4;
    float* gp = (float*)&g4;
#pragma unroll
    for (int g = 0; g < 4; ++g) {
        float acc = 0.f;
#pragma unroll
        for (int j = 0; j < 21; ++j) acc = fmaf(wi0[g][j], x[j], acc);
        gp[g] = acc;
    }
    *(float4*)&lds[t * 36 + sl * 4] = g4;
    __syncthreads();

    const int tG = tid >> 3, j = tid & 7;
    float4 val = *(const float4*)&lds[tG * 36 + j * 4];
    xg[(size_t)tG * k + s0 + j] = val;
}

// ---------------- Kernel B: recurrence (coalesced gate reads, all in flight) ---
__global__ __launch_bounds__(256, 1)
void recur_kernel(const float4* __restrict__ xg, const float* __restrict__ wihr,
                  const float* __restrict__ whhp, float* __restrict__ out,
                  double* __restrict__ wsd, float* __restrict__ wsy, int k)
{
    const int s = blockIdx.x * 256 + threadIdx.x;

    float wir[4][4];
#pragma unroll
    for (int l = 0; l < 4; ++l)
#pragma unroll
        for (int g = 0; g < 4; ++g) wir[l][g] = wihr[l * 4 + g];
    float whh[5][4];
#pragma unroll
    for (int l = 0; l < 5; ++l)
#pragma unroll
        for (int g = 0; g < 4; ++g) whh[l][g] = whhp[l * 4 + g];

    float4 gbuf[T];
#pragma unroll
    for (int t = 0; t < T; ++t) gbuf[t] = xg[(size_t)t * k + s];

    float h[5] = {0.f, 0.f, 0.f, 0.f, 0.f};
    float c[5] = {0.f, 0.f, 0.f, 0.f, 0.f};
    float y0 = 0.f;

#pragma unroll
    for (int t = 0; t < T; ++t) {
        const float4 G = gbuf[t];
        float a0 = fmaf(whh[0][0], h[0], G.x);
        float a1 = fmaf(whh[0][1], h[0], G.y);
        float a2 = fmaf(whh[0][2], h[0], G.z);
        float a3 = fmaf(whh[0][3], h[0], G.w);
        {
            float ii = sigm(a0), ff = sigm(a1);
            float gg = tanh_fast(a2), oo = sigm(a3);
            c[0] = ff * c[0] + ii * gg;
            h[0] = oo * tanh_fast(c[0]);
        }
        float xin = h[0];
#pragma unroll
        for (int l = 1; l < 5; ++l) {
            float b0 = fmaf(wir[l - 1][0], xin, whh[l][0] * h[l]);
            float b1 = fmaf(wir[l - 1][1], xin, whh[l][1] * h[l]);
            float b2 = fmaf(wir[l - 1][2], xin, whh[l][2] * h[l]);
            float b3 = fmaf(wir[l - 1][3], xin, whh[l][3] * h[l]);
            float ii = sigm(b0), ff = sigm(b1);
            float gg = tanh_fast(b2), oo = sigm(b3);
            c[l] = ff * c[l] + ii * gg;
            h[l] = oo * tanh_fast(c[l]);
            xin = h[l];
        }
        if (t == 0) y0 = h[4];
    }

#pragma unroll
    for (int l = 0; l < 5; ++l) {
        out[(size_t)6 * k + (size_t)l * k + s] = h[l];
        out[(size_t)11 * k + (size_t)l * k + s] = c[l];
    }
    wsy[s] = y0;

    float ys = y0, yq = y0 * y0;
#pragma unroll
    for (int off = 32; off; off >>= 1) {
        ys += __shfl_down(ys, off);
        yq += __shfl_down(yq, off);
    }
    __shared__ float pS[4], pQ[4];
    const int wid = threadIdx.x >> 6, lane = threadIdx.x & 63;
    if (lane == 0) { pS[wid] = ys; pQ[wid] = yq; }
    __syncthreads();
    if (threadIdx.x == 0) {
        atomicAdd(&wsd[0], (double)(pS[0] + pS[1] + pS[2] + pS[3]));
        atomicAdd(&wsd[1], (double)(pQ[0] + pQ[1] + pQ[2] + pQ[3]));
    }
}

// ---------------- fallback fused LSTM (round-0 structure, known 98 us) --------
__global__ __launch_bounds__(256, 1)
void lstm_fused(const float* __restrict__ r, const float* __restrict__ v,
                const float* __restrict__ u,
                const float* __restrict__ wih0, const float* __restrict__ wihr,
                const float* __restrict__ whhp,
                float* __restrict__ out, double* __restrict__ wsd,
                float* __restrict__ wsy, int k)
{
    const int s = blockIdx.x * 256 + threadIdx.x;
    float wi0[4][21];
#pragma unroll
    for (int g = 0; g < 4; ++g)
#pragma unroll
        for (int j = 0; j < 21; ++j) wi0[g][j] = wih0[g * 21 + j];
    float wir[4][4];
#pragma unroll
    for (int l = 0; l < 4; ++l)
#pragma unroll
        for (int g = 0; g < 4; ++g) wir[l][g] = wihr[l * 4 + g];
    float whh[5][4];
#pragma unroll
    for (int l = 0; l < 5; ++l)
#pragma unroll
        for (int g = 0; g < 4; ++g) whh[l][g] = whhp[l * 4 + g];

    const float4* r4 = reinterpret_cast<const float4*>(r + (size_t)s * (T * 9));
    const float4* v4 = reinterpret_cast<const float4*>(v + (size_t)s * (T * 6));
    const float4* u4 = reinterpret_cast<const float4*>(u + (size_t)s * (T * 6));

    float h[5] = {0.f, 0.f, 0.f, 0.f, 0.f};
    float c[5] = {0.f, 0.f, 0.f, 0.f, 0.f};
    float y0 = 0.f;

    for (int t0 = 0; t0 < T; t0 += 4) {
        const int cb = t0 >> 2;
        float4 rb[9], vb[6], ub[6];
#pragma unroll
        for (int q = 0; q < 9; ++q) rb[q] = r4[cb * 9 + q];
#pragma unroll
        for (int q = 0; q < 6; ++q) vb[q] = v4[cb * 6 + q];
#pragma unroll
        for (int q = 0; q < 6; ++q) ub[q] = u4[cb * 6 + q];
        float rf[36], vf[24], uf[24];
#pragma unroll
        for (int q = 0; q < 9; ++q) {
            rf[4 * q] = rb[q].x; rf[4 * q + 1] = rb[q].y;
            rf[4 * q + 2] = rb[q].z; rf[4 * q + 3] = rb[q].w;
        }
#pragma unroll
        for (int q = 0; q < 6; ++q) {
            vf[4 * q] = vb[q].x; vf[4 * q + 1] = vb[q].y;
            vf[4 * q + 2] = vb[q].z; vf[4 * q + 3] = vb[q].w;
            uf[4 * q] = ub[q].x; uf[4 * q + 1] = ub[q].y;
            uf[4 * q + 2] = ub[q].z; uf[4 * q + 3] = ub[q].w;
        }
#pragma unroll
        for (int dt = 0; dt < 4; ++dt) {
            float x[21];
#pragma unroll
            for (int j = 0; j < 9; ++j) x[j] = rf[dt * 9 + j];
#pragma unroll
            for (int j = 0; j < 6; ++j) x[9 + j] = vf[dt * 6 + j];
#pragma unroll
            for (int j = 0; j < 6; ++j) x[15 + j] = uf[dt * 6 + j];
            float gt[4];
#pragma unroll
            for (int g = 0; g < 4; ++g) {
                float a = whh[0][g] * h[0];
#pragma unroll
                for (int j = 0; j < 21; ++j) a = fmaf(wi0[g][j], x[j], a);
                gt[g] = a;
            }
            {
                float ii = sigm(gt[0]), ff = sigm(gt[1]);
                float gg = tanh_fast(gt[2]), oo = sigm(gt[3]);
                c[0] = ff * c[0] + ii * gg;
                h[0] = oo * tanh_fast(c[0]);
            }
            float xin = h[0];
#pragma unroll
            for (int l = 1; l < 5; ++l) {
                float b0 = fmaf(wir[l - 1][0], xin, whh[l][0] * h[l]);
                float b1 = fmaf(wir[l - 1][1], xin, whh[l][1] * h[l]);
                float b2 = fmaf(wir[l - 1][2], xin, whh[l][2] * h[l]);
                float b3 = fmaf(wir[l - 1][3], xin, whh[l][3] * h[l]);
                float ii = sigm(b0), ff = sigm(b1);
                float gg = tanh_fast(b2), oo = sigm(b3);
                c[l] = ff * c[l] + ii * gg;
                h[l] = oo * tanh_fast(c[l]);
                xin = h[l];
            }
            if (t0 + dt == 0) y0 = h[4];
        }
    }
#pragma unroll
    for (int l = 0; l < 5; ++l) {
        out[(size_t)6 * k + (size_t)l * k + s] = h[l];
        out[(size_t)11 * k + (size_t)l * k + s] = c[l];
    }
    wsy[s] = y0;
    float ys = y0, yq = y0 * y0;
#pragma unroll
    for (int off = 32; off; off >>= 1) {
        ys += __shfl_down(ys, off);
        yq += __shfl_down(yq, off);
    }
    __shared__ float pS[4], pQ[4];
    const int wid = threadIdx.x >> 6, lane = threadIdx.x & 63;
    if (lane == 0) { pS[wid] = ys; pQ[wid] = yq; }
    __syncthreads();
    if (threadIdx.x == 0) {
        atomicAdd(&wsd[0], (double)(pS[0] + pS[1] + pS[2] + pS[3]));
        atomicAdd(&wsd[1], (double)(pQ[0] + pQ[1] + pQ[2] + pQ[3]));
    }
}

// ---------------- FC chain ---------------------------------------------------
__global__ __launch_bounds__(256)
void hist_kernel(const float* __restrict__ W1, const float* __restrict__ g1,
                 const float* __restrict__ b1, double* __restrict__ wsd,
                 const float* __restrict__ wsy, int k)
{
    __shared__ float sTau[32];
    __shared__ float sH[3 * NREG];
    __shared__ float sMy;
    const int tid = threadIdx.x;
    if (tid < 3 * NREG) sH[tid] = 0.f;
    if (tid < 32) {
        float my, vy, a, b, tau; int flip;
        bn1_params(W1, g1, b1, wsd, k, tid, my, vy, a, b, tau, flip);
        sTau[tid] = tau;
        if (tid == 0) sMy = my;
    }
    __syncthreads();
    const int stride = gridDim.x * 256;
    for (int s = blockIdx.x * 256 + tid; s < k; s += stride) {
        const float y = wsy[s];
        const float yc = y - sMy;
        int rgn = 0;
#pragma unroll
        for (int j = 0; j < 32; ++j) rgn += (y > sTau[j]) ? 1 : 0;
        atomicAdd(&sH[rgn], 1.0f);
        atomicAdd(&sH[NREG + rgn], yc);
        atomicAdd(&sH[2 * NREG + rgn], yc * yc);
    }
    __syncthreads();
    if (tid < 3 * NREG) atomicAdd(&wsd[2 + tid], (double)sH[tid]);
}

__global__ __launch_bounds__(256)
void tables_kernel(const float* __restrict__ W1, const float* __restrict__ g1,
                   const float* __restrict__ b1, const float* __restrict__ W2,
                   const float* __restrict__ g2, const float* __restrict__ b2,
                   const double* __restrict__ wsd, float* __restrict__ gPQ, int k)
{
    __shared__ float sA[32], sB[32], sTau[32];
    __shared__ int sRank[32], sFlip[32];
    __shared__ float sS0[NREG], sS1[NREG], sS2[NREG];
    __shared__ float sW2[1024];
    __shared__ float sSumY1[32];
    __shared__ float sM[1024];
    __shared__ float sI2[32], sM2v[32], sB2[32];
    const int tid = threadIdx.x;

    for (int i = tid; i < 1024; i += 256) sW2[i] = W2[i];
    if (tid < NREG) {
        sS0[tid] = (float)wsd[2 + tid];
        sS1[tid] = (float)wsd[2 + NREG + tid];
        sS2[tid] = (float)wsd[2 + 2 * NREG + tid];
    }
    if (tid < 32) {
        float my, vy, a, b, tau; int flip;
        bn1_params(W1, g1, b1, wsd, k, tid, my, vy, a, b, tau, flip);
        sA[tid] = a; sB[tid] = b; sTau[tid] = tau; sFlip[tid] = flip;
        sB2[tid] = b2[tid];
    }
    __syncthreads();
    if (tid < 32) {
        int rk = 0;
        float tj = sTau[tid];
#pragma unroll
        for (int l = 0; l < 32; ++l)
            rk += (sTau[l] < tj || (sTau[l] == tj && l < tid)) ? 1 : 0;
        sRank[tid] = rk;
    }
    __syncthreads();
    if (tid < 32) {
        const int rk = sRank[tid], fl = sFlip[tid];
        const float a = sA[tid], b = sB[tid];
        float acc = 0.f;
        for (int rg = 0; rg < NREG; ++rg) {
            float m = (((rk < rg) ? 1 : 0) != fl) ? 1.0f : NEGS;
            acc += m * (a * sS1[rg] + b * sS0[rg]);
        }
        sSumY1[tid] = acc;
    }
    for (int p = tid; p < 1024; p += 256) {
        const int j = p >> 5, l = p & 31;
        const int rj = sRank[j], fj = sFlip[j];
        const int rl = sRank[l], flp = sFlip[l];
        const float aj = sA[j], bj = sB[j], al = sA[l], bl = sB[l];
        const float caa = aj * al, cab = aj * bl + al * bj, cbb = bj * bl;
        float acc = 0.f;
        for (int rg = 0; rg < NREG; ++rg) {
            float mj = (((rj < rg) ? 1 : 0) != fj) ? 1.0f : NEGS;
            float ml = (((rl < rg) ? 1 : 0) != flp) ? 1.0f : NEGS;
            acc += mj * ml * (caa * sS2[rg] + cab * sS1[rg] + cbb * sS0[rg]);
        }
        sM[p] = acc;
    }
    __syncthreads();
    if (tid < 32) {
        const int i = tid;
        float s2 = 0.f, ss2 = 0.f;
#pragma unroll
        for (int j = 0; j < 32; ++j) {
            float wij = sW2[i * 32 + j];
            s2 = fmaf(wij, sSumY1[j], s2);
            float tj = 0.f;
#pragma unroll
            for (int l = 0; l < 32; ++l) tj = fmaf(sW2[i * 32 + l], sM[j * 32 + l], tj);
            ss2 = fmaf(wij, tj, ss2);
        }
        float m2 = s2 / k;
        float v2 = ss2 / k - m2 * m2;
        sM2v[i] = m2;
        sI2[i] = g2[i] * rsqrtf(v2 + EPS);
    }
    __syncthreads();
    for (int idx = tid; idx < NREG * 32; idx += 256) {
        const int rg = idx >> 5, i = idx & 31;
        float Ai = 0.f, Bi = 0.f;
#pragma unroll
        for (int j = 0; j < 32; ++j) {
            float m = (((sRank[j] < rg) ? 1 : 0) != sFlip[j]) ? 1.0f : NEGS;
            float w = sW2[i * 32 + j] * m;
            Ai = fmaf(w, sA[j], Ai);
            Bi = fmaf(w, sB[j], Bi);
        }
        gPQ[idx] = sI2[i] * Ai;
        gPQ[NREG * 32 + idx] = sI2[i] * (Bi - sM2v[i]) + sB2[i];
    }
}

__global__ __launch_bounds__(256)
void final_kernel(const float* __restrict__ W1, const float* __restrict__ g1,
                  const float* __restrict__ b1, const float* __restrict__ W3,
                  const double* __restrict__ wsd, const float* __restrict__ wsy,
                  const float* __restrict__ gPQ, float* __restrict__ out, int k)
{
    __shared__ float sTau[32], sW3[192], sMy;
    __shared__ float sP[NREG][33], sQ[NREG][33];
    const int tid = threadIdx.x;
    for (int idx = tid; idx < NREG * 32; idx += 256) {
        const int rg = idx >> 5, i = idx & 31;
        sP[rg][i] = gPQ[idx];
        sQ[rg][i] = gPQ[NREG * 32 + idx];
    }
    if (tid < 192) sW3[tid] = W3[tid];
    if (tid < 32) {
        float my, vy, a, b, tau; int flip;
        bn1_params(W1, g1, b1, wsd, k, tid, my, vy, a, b, tau, flip);
        sTau[tid] = tau;
        if (tid == 0) sMy = my;
    }
    __syncthreads();
    const int s = blockIdx.x * 256 + tid;
    const float y = wsy[s];
    const float yc = y - sMy;
    int rgn = 0;
#pragma unroll
    for (int j = 0; j < 32; ++j) rgn += (y > sTau[j]) ? 1 : 0;
    float dv[6] = {0.f, 0.f, 0.f, 0.f, 0.f, 0.f};
#pragma unroll
    for (int i = 0; i < 32; ++i) {
        float y2 = lrelu(fmaf(sP[rgn][i], yc, sQ[rgn][i]));
#pragma unroll
        for (int m = 0; m < 6; ++m) dv[m] = fmaf(sW3[m * 32 + i], y2, dv[m]);
    }
#pragma unroll
    for (int m = 0; m < 6; ++m) out[(size_t)s * 6 + m] = dv[m];
}

extern "C" void kernel_launch(void* const* d_in, const int* in_sizes, int n_in,
                              void* d_out, int out_size, void* d_ws, size_t ws_size,
                              hipStream_t stream)
{
    const float* r    = (const float*)d_in[0];
    const float* v    = (const float*)d_in[1];
    const float* u    = (const float*)d_in[2];
    const float* wih0 = (const float*)d_in[3];
    const float* wihr = (const float*)d_in[4];
    const float* whhp = (const float*)d_in[5];
    const float* W1   = (const float*)d_in[6];
    const float* g1v  = (const float*)d_in[7];
    const float* b1v  = (const float*)d_in[8];
    const float* W2   = (const float*)d_in[9];
    const float* g2v  = (const float*)d_in[10];
    const float* b2v  = (const float*)d_in[11];
    const float* W3   = (const float*)d_in[12];

    const int k = in_sizes[0] / (T * 9);   // 65536
    float* out = (float*)d_out;
    double* wsd = (double*)d_ws;
    float* wsy = (float*)((char*)d_ws + 1024);

    const size_t xg_off = 1024 + (size_t)k * 4;
    const size_t need = xg_off + (size_t)k * T * 16 + (size_t)NREG * 32 * 2 * 4;

    hipMemsetAsync(d_ws, 0, 1024, stream);

    const int blocks = k / 256;
    float* gPQ;
    if (ws_size >= need) {
        float4* xg = (float4*)((char*)d_ws + xg_off);
        gPQ = (float*)((char*)d_ws + xg_off + (size_t)k * T * 16);
        gates_kernel<<<k / 8, 256, 0, stream>>>(r, v, u, wih0, xg, k);
        recur_kernel<<<blocks, 256, 0, stream>>>(xg, wihr, whhp, out, wsd, wsy, k);
    } else {
        gPQ = (float*)((char*)d_ws + xg_off);
        lstm_fused<<<blocks, 256, 0, stream>>>(r, v, u, wih0, wihr, whhp, out, wsd, wsy, k);
    }
    hist_kernel<<<64, 256, 0, stream>>>(W1, g1v, b1v, wsd, wsy, k);
    tables_kernel<<<1, 256, 0, stream>>>(W1, g1v, b1v, W2, g2v, b2v, wsd, gPQ, k);
    final_kernel<<<blocks, 256, 0, stream>>>(W1, g1v, b1v, W3, wsd, wsy, gPQ, out, k);
}